// Round 2
// baseline (808.270 us; speedup 1.0000x reference)
//
#include <hip/hip_runtime.h>

typedef __attribute__((ext_vector_type(8))) short short8;
typedef __attribute__((ext_vector_type(4))) float floatx4;

constexpr int DIM = 128;   // dim_in == dim_out
constexpr int NB  = 4;     // bases
constexpr int NR  = 8;     // relations

static __device__ __forceinline__ unsigned short f2bf(float f) {
    // round-to-nearest-even fp32 -> bf16 (bit trick; inputs finite)
    unsigned int u = __float_as_uint(f);
    u += 0x7FFFu + ((u >> 16) & 1u);
    return (unsigned short)(u >> 16);
}

// ---------------------------------------------------------------------------
// K1: build W_r = sum_b A[r,b] * V[b] in bf16, pre-swizzled into MFMA
// B-operand fragment layout:
//   Wfrag[r][ot][ks][lane][j]  (j=0..7, 16B per lane)
//   value = W[r][k][o], k = ks*32 + (lane>>4)*8 + j, o = ot*16 + (lane&15)
// ---------------------------------------------------------------------------
__global__ __launch_bounds__(256) void build_wfrag(
    const float* __restrict__ A, const float* __restrict__ V,
    unsigned short* __restrict__ Wfrag)
{
    int idx  = blockIdx.x * 256 + threadIdx.x;   // 0 .. 16383
    int lane = idx & 63;
    int ks   = (idx >> 6) & 3;
    int ot   = (idx >> 8) & 7;
    int r    = idx >> 11;

    int o     = ot * 16 + (lane & 15);
    int kbase = ks * 32 + (lane >> 4) * 8;

    float a0 = A[r * NB + 0], a1 = A[r * NB + 1];
    float a2 = A[r * NB + 2], a3 = A[r * NB + 3];

    short8 v;
#pragma unroll
    for (int j = 0; j < 8; ++j) {
        int k = kbase + j;
        float w = a0 * V[(0 * DIM + k) * DIM + o]
                + a1 * V[(1 * DIM + k) * DIM + o]
                + a2 * V[(2 * DIM + k) * DIM + o]
                + a3 * V[(3 * DIM + k) * DIM + o];
        v[j] = (short)f2bf(w);
    }
    *reinterpret_cast<short8*>(Wfrag + (size_t)idx * 8) = v;
}

// ---------------------------------------------------------------------------
// K2: H (fp32) -> Hbf (bf16), row-major [Ne][128]
// ---------------------------------------------------------------------------
__global__ __launch_bounds__(256) void h_to_bf(
    const float* __restrict__ H, unsigned short* __restrict__ Hbf, int n8)
{
    int i = blockIdx.x * 256 + threadIdx.x;
    if (i >= n8) return;
    const float4* hp = reinterpret_cast<const float4*>(H) + (size_t)i * 2;
    float4 f0 = hp[0];
    float4 f1 = hp[1];
    short8 v;
    v[0] = (short)f2bf(f0.x); v[1] = (short)f2bf(f0.y);
    v[2] = (short)f2bf(f0.z); v[3] = (short)f2bf(f0.w);
    v[4] = (short)f2bf(f1.x); v[5] = (short)f2bf(f1.y);
    v[6] = (short)f2bf(f1.z); v[7] = (short)f2bf(f1.w);
    *reinterpret_cast<short8*>(Hbf + (size_t)i * 8) = v;
}

// ---------------------------------------------------------------------------
// K3: fused gather -> (16 edges x 128) @ W_r -> scale by val -> atomic scatter
// One wave processes groups of 16 edges of its fixed relation.
// Relations interleaved across waves (r = wid & 7) so every CU mixes all
// relations' atomic destinations.
// ---------------------------------------------------------------------------
__global__ __launch_bounds__(256, 4) void rgcn_main(
    const unsigned short* __restrict__ Hbf,
    const unsigned short* __restrict__ Wfrag,
    const int*   __restrict__ erow,
    const int*   __restrict__ ecol,
    const float* __restrict__ eval,
    float*       __restrict__ out,
    int E, int groups_per_rel, int waves_per_rel)
{
    int wid  = blockIdx.x * 4 + (threadIdx.x >> 6);
    int lane = threadIdx.x & 63;
    int r    = wid & 7;            // relation interleave
    int wr   = wid >> 3;
    int quad = lane >> 4;
    int l15  = lane & 15;

    // Load this relation's W fragments into registers (held for whole kernel)
    short8 b[8][4];
    {
        const short8* wp = reinterpret_cast<const short8*>(
            Wfrag + ((size_t)r * 8 * 4 * 64) * 8);
#pragma unroll
        for (int ot = 0; ot < 8; ++ot)
#pragma unroll
            for (int ks = 0; ks < 4; ++ks)
                b[ot][ks] = wp[(ot * 4 + ks) * 64 + lane];
    }

    for (int g = wr; g < groups_per_rel; g += waves_per_rel) {
        int ebase = r * E + g * 16;

        int   colv = ecol[ebase + l15];
        int   rowv = erow[ebase + l15];
        float valv = eval[ebase + l15];

        // gather A fragments: lane reads 4x16B from row colv
        short8 a[4];
        const unsigned short* hp = Hbf + (size_t)colv * DIM + quad * 8;
#pragma unroll
        for (int ks = 0; ks < 4; ++ks)
            a[ks] = *reinterpret_cast<const short8*>(hp + ks * 32);

        floatx4 acc[8];
#pragma unroll
        for (int ot = 0; ot < 8; ++ot) acc[ot] = (floatx4){0.f, 0.f, 0.f, 0.f};

#pragma unroll
        for (int ot = 0; ot < 8; ++ot)
#pragma unroll
            for (int ks = 0; ks < 4; ++ks)
                acc[ot] = __builtin_amdgcn_mfma_f32_16x16x32_bf16(
                    a[ks], b[ot][ks], acc[ot], 0, 0, 0);

        // rows / vals for the 4 D-rows this lane's quad owns
        int   row4[4];
        float val4[4];
#pragma unroll
        for (int reg = 0; reg < 4; ++reg) {
            int src  = quad * 4 + reg;
            row4[reg] = __shfl(rowv, src, 64);
            val4[reg] = __shfl(valv, src, 64);
        }

#pragma unroll
        for (int ot = 0; ot < 8; ++ot) {
#pragma unroll
            for (int reg = 0; reg < 4; ++reg) {
                float m = acc[ot][reg] * val4[reg];
                atomicAdd(out + (size_t)row4[reg] * DIM + ot * 16 + l15, m);
            }
        }
    }
}

extern "C" void kernel_launch(void* const* d_in, const int* in_sizes, int n_in,
                              void* d_out, int out_size, void* d_ws, size_t ws_size,
                              hipStream_t stream)
{
    const float* H    = (const float*)d_in[0];
    const float* A    = (const float*)d_in[1];
    const float* V    = (const float*)d_in[2];
    const int*   erow = (const int*)d_in[3];
    const int*   ecol = (const int*)d_in[4];
    const float* eval = (const float*)d_in[5];
    float* out = (float*)d_out;

    int Ne = in_sizes[0] / DIM;          // 100000
    int E  = in_sizes[3] / NR;           // 200000

    // workspace layout
    unsigned short* Hbf   = (unsigned short*)d_ws;                  // Ne*128 bf16
    unsigned short* Wfrag = Hbf + (size_t)Ne * DIM;                 // 16384*8 bf16

    // zero the output accumulator
    hipMemsetAsync(d_out, 0, (size_t)Ne * DIM * sizeof(float), stream);

    // K1: W fragments
    build_wfrag<<<64, 256, 0, stream>>>(A, V, Wfrag);

    // K2: H -> bf16
    int n8 = Ne * DIM / 8;
    h_to_bf<<<(n8 + 255) / 256, 256, 0, stream>>>(H, Hbf, n8);

    // K3: main fused kernel — 8x the waves of round 1
    int blocks = 4096;                      // 16384 waves, 2048 per relation
    int waves_per_rel = blocks * 4 / NR;
    int groups_per_rel = E / 16;            // 12500
    rgcn_main<<<blocks, 256, 0, stream>>>(Hbf, Wfrag, erow, ecol, eval, out,
                                          E, groups_per_rel, waves_per_rel);
}

// Round 3
// 495.596 us; speedup vs baseline: 1.6309x; 1.6309x over previous
//
#include <hip/hip_runtime.h>

typedef __attribute__((ext_vector_type(8))) short short8;
typedef __attribute__((ext_vector_type(4))) float floatx4;

constexpr int DIM = 128;   // dim_in == dim_out
constexpr int NB  = 4;     // bases
constexpr int NR  = 8;     // relations

static __device__ __forceinline__ unsigned short f2bf(float f) {
    unsigned int u = __float_as_uint(f);
    u += 0x7FFFu + ((u >> 16) & 1u);
    return (unsigned short)(u >> 16);
}
static __device__ __forceinline__ float bf_lo(unsigned int h) {
    return __uint_as_float(h << 16);
}
static __device__ __forceinline__ float bf_hi(unsigned int h) {
    return __uint_as_float(h & 0xFFFF0000u);
}

// ---------------------------------------------------------------------------
// K1: W_r = sum_b A[r,b]*V[b] in bf16, MFMA fragment layout.
// Wfrag[r][ot][ks][lane][j] = W[r][k][o], k=ks*32+(lane>>4)*8+j, o=ot*16+(lane&15)
// This layout serves as EITHER the A operand (m=o) or B operand (n=o) of
// v_mfma_f32_16x16x32_bf16 (per-lane layouts of A and B are identical).
// ---------------------------------------------------------------------------
__global__ __launch_bounds__(256) void build_wfrag(
    const float* __restrict__ A, const float* __restrict__ V,
    unsigned short* __restrict__ Wfrag)
{
    int idx  = blockIdx.x * 256 + threadIdx.x;   // 0 .. 16383
    int lane = idx & 63;
    int ks   = (idx >> 6) & 3;
    int ot   = (idx >> 8) & 7;
    int r    = idx >> 11;

    int o     = ot * 16 + (lane & 15);
    int kbase = ks * 32 + (lane >> 4) * 8;

    float a0 = A[r * NB + 0], a1 = A[r * NB + 1];
    float a2 = A[r * NB + 2], a3 = A[r * NB + 3];

    short8 v;
#pragma unroll
    for (int j = 0; j < 8; ++j) {
        int k = kbase + j;
        float w = a0 * V[(0 * DIM + k) * DIM + o]
                + a1 * V[(1 * DIM + k) * DIM + o]
                + a2 * V[(2 * DIM + k) * DIM + o]
                + a3 * V[(3 * DIM + k) * DIM + o];
        v[j] = (short)f2bf(w);
    }
    *reinterpret_cast<short8*>(Wfrag + (size_t)idx * 8) = v;
}

// ---------------------------------------------------------------------------
// K2: H (fp32) -> Hbf (bf16), row-major [Ne][128]
// ---------------------------------------------------------------------------
__global__ __launch_bounds__(256) void h_to_bf(
    const float* __restrict__ H, unsigned short* __restrict__ Hbf, int n8)
{
    int i = blockIdx.x * 256 + threadIdx.x;
    if (i >= n8) return;
    const float4* hp = reinterpret_cast<const float4*>(H) + (size_t)i * 2;
    float4 f0 = hp[0];
    float4 f1 = hp[1];
    short8 v;
    v[0] = (short)f2bf(f0.x); v[1] = (short)f2bf(f0.y);
    v[2] = (short)f2bf(f0.z); v[3] = (short)f2bf(f0.w);
    v[4] = (short)f2bf(f1.x); v[5] = (short)f2bf(f1.y);
    v[6] = (short)f2bf(f1.z); v[7] = (short)f2bf(f1.w);
    *reinterpret_cast<short8*>(Hbf + (size_t)i * 8) = v;
}

// ---------------------------------------------------------------------------
// K3: dense HxW[r] = Hbf @ W_r  (bf16 out), all relations.
// Swapped-operand MFMA: A = Wfrag (m = o), B = H-frag (n = node).
// D[row=o_local=quad*4+reg][col=node=l15]; per lane, reg 0..3 are 4
// consecutive o -> one 8B ushort4 store per ot.
// ---------------------------------------------------------------------------
__global__ __launch_bounds__(256) void hxw_kernel(
    const unsigned short* __restrict__ Hbf,
    const unsigned short* __restrict__ Wfrag,
    unsigned short* __restrict__ HxW,
    int Ne, int tilesPerRel, int wavesPerRel)
{
    int wid  = blockIdx.x * 4 + (threadIdx.x >> 6);
    int lane = threadIdx.x & 63;
    int quad = lane >> 4;
    int l15  = lane & 15;
    int r    = wid & 7;
    int wr   = wid >> 3;

    // W_r fragments, register-resident (A operand)
    short8 w[8][4];
    const short8* wp = reinterpret_cast<const short8*>(Wfrag + (size_t)r * 16384);
#pragma unroll
    for (int ot = 0; ot < 8; ++ot)
#pragma unroll
        for (int ks = 0; ks < 4; ++ks)
            w[ot][ks] = wp[(ot * 4 + ks) * 64 + lane];

    for (int tile = wr; tile < tilesPerRel; tile += wavesPerRel) {
        int node0 = tile * 16;

        // B frag: B[k][n=node=l15] = Hbf[node0+l15][k]
        short8 h[4];
        const unsigned short* hp = Hbf + (size_t)(node0 + l15) * DIM + quad * 8;
#pragma unroll
        for (int ks = 0; ks < 4; ++ks)
            h[ks] = *reinterpret_cast<const short8*>(hp + ks * 32);

        floatx4 acc[8];
#pragma unroll
        for (int ot = 0; ot < 8; ++ot) acc[ot] = (floatx4){0.f, 0.f, 0.f, 0.f};

#pragma unroll
        for (int ot = 0; ot < 8; ++ot)
#pragma unroll
            for (int ks = 0; ks < 4; ++ks)
                acc[ot] = __builtin_amdgcn_mfma_f32_16x16x32_bf16(
                    w[ot][ks], h[ks], acc[ot], 0, 0, 0);

        unsigned short* orow = HxW + ((size_t)r * Ne + node0 + l15) * DIM;
#pragma unroll
        for (int ot = 0; ot < 8; ++ot) {
            ushort4 pk;
            pk.x = f2bf(acc[ot][0]);
            pk.y = f2bf(acc[ot][1]);
            pk.z = f2bf(acc[ot][2]);
            pk.w = f2bf(acc[ot][3]);
            *reinterpret_cast<ushort4*>(orow + ot * 16 + quad * 4) = pk;
        }
    }
}

// ---------------------------------------------------------------------------
// Counting sort of edges by destination row
// ---------------------------------------------------------------------------
__global__ __launch_bounds__(256) void hist_kernel(
    const int* __restrict__ erow, int* __restrict__ cnt, int n)
{
    int i = blockIdx.x * 256 + threadIdx.x;
    if (i < n) atomicAdd(cnt + erow[i], 1);
}

__global__ __launch_bounds__(256) void scan1(
    const int* __restrict__ cnt, int* __restrict__ rowStart,
    int* __restrict__ blockSums, int Ne)
{
    __shared__ int sd[256];
    int t = threadIdx.x, i = blockIdx.x * 256 + t;
    int c = (i < Ne) ? cnt[i] : 0;
    sd[t] = c; __syncthreads();
#pragma unroll
    for (int off = 1; off < 256; off <<= 1) {
        int v = (t >= off) ? sd[t - off] : 0;
        __syncthreads();
        sd[t] += v;
        __syncthreads();
    }
    if (i < Ne) rowStart[i] = sd[t] - c;
    if (t == 255) blockSums[blockIdx.x] = sd[t];
}

__global__ __launch_bounds__(512) void scan2(
    int* __restrict__ blockSums, int* __restrict__ rowStart, int nb, int Ne)
{
    __shared__ int sd[512];
    int t = threadIdx.x;
    int c = (t < nb) ? blockSums[t] : 0;
    sd[t] = c; __syncthreads();
#pragma unroll
    for (int off = 1; off < 512; off <<= 1) {
        int v = (t >= off) ? sd[t - off] : 0;
        __syncthreads();
        sd[t] += v;
        __syncthreads();
    }
    if (t < nb) blockSums[t] = sd[t] - c;
    if (t == nb - 1) rowStart[Ne] = sd[t];
}

__global__ __launch_bounds__(256) void scan3(
    int* __restrict__ rowStart, const int* __restrict__ blockSums, int Ne)
{
    int i = blockIdx.x * 256 + threadIdx.x;
    if (i < Ne) rowStart[i] += blockSums[blockIdx.x];
}

__global__ __launch_bounds__(256) void scatter_kernel(
    const int* __restrict__ erow, const int* __restrict__ ecol,
    const float* __restrict__ eval, int* __restrict__ cursor,
    int* __restrict__ sKey, float* __restrict__ sVal, int n, int E)
{
    int i = blockIdx.x * 256 + threadIdx.x;
    if (i >= n) return;
    int row = erow[i];
    int col = ecol[i];
    float v = eval[i];
    int r = (int)((unsigned)i / (unsigned)E);
    int pos = atomicAdd(cursor + row, 1);
    sKey[pos] = (r << 20) | col;
    sVal[pos] = v;
}

// ---------------------------------------------------------------------------
// K4: accumulate. One wave per destination row; lane owns 2 output cols.
// Reads are 256B coalesced gathers from HxW (mostly L3); out written once.
// ---------------------------------------------------------------------------
__global__ __launch_bounds__(256) void accum_kernel(
    const unsigned short* __restrict__ HxW,
    const int* __restrict__ rowStart,
    const int* __restrict__ sKey,
    const float* __restrict__ sVal,
    float* __restrict__ out, int Ne)
{
    int wid = blockIdx.x * 4 + (threadIdx.x >> 6);
    if (wid >= Ne) return;
    int lane = threadIdx.x & 63;
    int s = rowStart[wid], e = rowStart[wid + 1];

    float ax = 0.f, ay = 0.f;
    int i = s;
    for (; i + 1 < e; i += 2) {
        int k0 = sKey[i],   k1 = sKey[i + 1];
        float v0 = sVal[i], v1 = sVal[i + 1];
        const unsigned int* p0 = reinterpret_cast<const unsigned int*>(
            HxW + ((size_t)(k0 >> 20) * Ne + (k0 & 0xFFFFF)) * DIM) + lane;
        const unsigned int* p1 = reinterpret_cast<const unsigned int*>(
            HxW + ((size_t)(k1 >> 20) * Ne + (k1 & 0xFFFFF)) * DIM) + lane;
        unsigned int h0 = *p0;
        unsigned int h1 = *p1;
        ax += v0 * bf_lo(h0); ay += v0 * bf_hi(h0);
        ax += v1 * bf_lo(h1); ay += v1 * bf_hi(h1);
    }
    if (i < e) {
        int k0 = sKey[i];
        float v0 = sVal[i];
        const unsigned int* p0 = reinterpret_cast<const unsigned int*>(
            HxW + ((size_t)(k0 >> 20) * Ne + (k0 & 0xFFFFF)) * DIM) + lane;
        unsigned int h0 = *p0;
        ax += v0 * bf_lo(h0); ay += v0 * bf_hi(h0);
    }
    float2 res; res.x = ax; res.y = ay;
    reinterpret_cast<float2*>(out)[(size_t)wid * 64 + lane] = res;
}

// ---------------------------------------------------------------------------
// Fallback (ws too small): round-2 atomic kernel
// ---------------------------------------------------------------------------
__global__ __launch_bounds__(256) void rgcn_main(
    const unsigned short* __restrict__ Hbf,
    const unsigned short* __restrict__ Wfrag,
    const int*   __restrict__ erow,
    const int*   __restrict__ ecol,
    const float* __restrict__ eval,
    float*       __restrict__ out,
    int E, int groups_per_rel, int waves_per_rel)
{
    int wid  = blockIdx.x * 4 + (threadIdx.x >> 6);
    int lane = threadIdx.x & 63;
    int r    = wid & 7;
    int wr   = wid >> 3;
    int quad = lane >> 4;
    int l15  = lane & 15;

    short8 b[8][4];
    {
        const short8* wp = reinterpret_cast<const short8*>(
            Wfrag + (size_t)r * 16384);
#pragma unroll
        for (int ot = 0; ot < 8; ++ot)
#pragma unroll
            for (int ks = 0; ks < 4; ++ks)
                b[ot][ks] = wp[(ot * 4 + ks) * 64 + lane];
    }

    for (int g = wr; g < groups_per_rel; g += waves_per_rel) {
        int ebase = r * E + g * 16;
        int   colv = ecol[ebase + l15];
        int   rowv = erow[ebase + l15];
        float valv = eval[ebase + l15];

        short8 a[4];
        const unsigned short* hp = Hbf + (size_t)colv * DIM + quad * 8;
#pragma unroll
        for (int ks = 0; ks < 4; ++ks)
            a[ks] = *reinterpret_cast<const short8*>(hp + ks * 32);

        floatx4 acc[8];
#pragma unroll
        for (int ot = 0; ot < 8; ++ot) acc[ot] = (floatx4){0.f, 0.f, 0.f, 0.f};
#pragma unroll
        for (int ot = 0; ot < 8; ++ot)
#pragma unroll
            for (int ks = 0; ks < 4; ++ks)
                acc[ot] = __builtin_amdgcn_mfma_f32_16x16x32_bf16(
                    a[ks], b[ot][ks], acc[ot], 0, 0, 0);

        int   row4[4];
        float val4[4];
#pragma unroll
        for (int reg = 0; reg < 4; ++reg) {
            int src  = quad * 4 + reg;
            row4[reg] = __shfl(rowv, src, 64);
            val4[reg] = __shfl(valv, src, 64);
        }
#pragma unroll
        for (int ot = 0; ot < 8; ++ot)
#pragma unroll
            for (int reg = 0; reg < 4; ++reg) {
                float m = acc[ot][reg] * val4[reg];
                atomicAdd(out + (size_t)row4[reg] * DIM + ot * 16 + l15, m);
            }
    }
}

extern "C" void kernel_launch(void* const* d_in, const int* in_sizes, int n_in,
                              void* d_out, int out_size, void* d_ws, size_t ws_size,
                              hipStream_t stream)
{
    const float* H    = (const float*)d_in[0];
    const float* A    = (const float*)d_in[1];
    const float* V    = (const float*)d_in[2];
    const int*   erow = (const int*)d_in[3];
    const int*   ecol = (const int*)d_in[4];
    const float* eval = (const float*)d_in[5];
    float* out = (float*)d_out;

    int Ne    = in_sizes[0] / DIM;   // 100000
    int NEtot = in_sizes[3];         // 1.6M
    int E     = NEtot / NR;          // 200000

    auto al = [](size_t x) { return (x + 255) & ~(size_t)255; };

    size_t offHbf   = 0;
    size_t offWfrag = offHbf   + al((size_t)Ne * DIM * 2);
    size_t offHxW   = offWfrag + al((size_t)16384 * 16);
    size_t offRow   = offHxW   + al((size_t)NR * Ne * DIM * 2);
    size_t offCur   = offRow   + al(((size_t)Ne + 2) * 4);
    size_t offBS    = offCur   + al((size_t)Ne * 4);
    size_t offKey   = offBS    + al((size_t)512 * 4);
    size_t offVal   = offKey   + al((size_t)NEtot * 4);
    size_t total    = offVal   + al((size_t)NEtot * 4);

    char* ws = (char*)d_ws;
    unsigned short* Hbf   = (unsigned short*)(ws + offHbf);
    unsigned short* Wfrag = (unsigned short*)(ws + offWfrag);

    // K1 + K2 (common)
    build_wfrag<<<64, 256, 0, stream>>>(A, V, Wfrag);
    int n8 = Ne * DIM / 8;
    h_to_bf<<<(n8 + 255) / 256, 256, 0, stream>>>(H, Hbf, n8);

    if (ws_size < total) {
        // fallback: atomic-scatter path (round 2)
        hipMemsetAsync(d_out, 0, (size_t)Ne * DIM * sizeof(float), stream);
        int blocks = 4096;
        int waves_per_rel = blocks * 4 / NR;
        int groups_per_rel = E / 16;
        rgcn_main<<<blocks, 256, 0, stream>>>(Hbf, Wfrag, erow, ecol, eval, out,
                                              E, groups_per_rel, waves_per_rel);
        return;
    }

    unsigned short* HxW      = (unsigned short*)(ws + offHxW);
    int*            rowStart = (int*)(ws + offRow);
    int*            cursor   = (int*)(ws + offCur);
    int*            blockSums= (int*)(ws + offBS);
    int*            sKey     = (int*)(ws + offKey);
    float*          sVal     = (float*)(ws + offVal);

    // K3: dense HxW (2048 blocks = 8192 waves, 1024 per relation)
    {
        int blocks = 2048;
        int wavesPerRel = blocks * 4 / NR;
        int tilesPerRel = (Ne + 15) / 16;
        hxw_kernel<<<blocks, 256, 0, stream>>>(Hbf, Wfrag, HxW, Ne,
                                               tilesPerRel, wavesPerRel);
    }

    // counting sort by destination row
    hipMemsetAsync(cursor, 0, (size_t)Ne * 4, stream);
    hist_kernel<<<(NEtot + 255) / 256, 256, 0, stream>>>(erow, cursor, NEtot);

    int nb1 = (Ne + 255) / 256;   // 391 <= 512
    scan1<<<nb1, 256, 0, stream>>>(cursor, rowStart, blockSums, Ne);
    scan2<<<1, 512, 0, stream>>>(blockSums, rowStart, nb1, Ne);
    scan3<<<nb1, 256, 0, stream>>>(rowStart, blockSums, Ne);

    hipMemcpyAsync(cursor, rowStart, (size_t)Ne * 4,
                   hipMemcpyDeviceToDevice, stream);
    scatter_kernel<<<(NEtot + 255) / 256, 256, 0, stream>>>(
        erow, ecol, eval, cursor, sKey, sVal, NEtot, E);

    // K4: accumulate, no atomics, out written exactly once
    accum_kernel<<<(Ne + 3) / 4, 256, 0, stream>>>(HxW, rowStart, sKey, sVal,
                                                   out, Ne);
}

// Round 4
// 447.295 us; speedup vs baseline: 1.8070x; 1.1080x over previous
//
#include <hip/hip_runtime.h>

typedef __attribute__((ext_vector_type(8))) short short8;
typedef __attribute__((ext_vector_type(4))) float floatx4;

constexpr int DIM = 128;   // dim_in == dim_out
constexpr int NB  = 4;     // bases
constexpr int NR  = 8;     // relations

static __device__ __forceinline__ unsigned short f2bf(float f) {
    unsigned int u = __float_as_uint(f);
    u += 0x7FFFu + ((u >> 16) & 1u);
    return (unsigned short)(u >> 16);
}
static __device__ __forceinline__ float bf_lo(unsigned int h) {
    return __uint_as_float(h << 16);
}
static __device__ __forceinline__ float bf_hi(unsigned int h) {
    return __uint_as_float(h & 0xFFFF0000u);
}

// ---------------------------------------------------------------------------
// Vfrag[b][ot][ks][lane][j] = V[b][k][o], k=ks*32+(lane>>4)*8+j, o=ot*16+(lane&15)
// (bf16, MFMA first-operand layout; same per-lane layout as verified Wfrag)
// ---------------------------------------------------------------------------
__global__ __launch_bounds__(256) void build_vfrag(
    const float* __restrict__ V, unsigned short* __restrict__ VfragG)
{
    int idx  = blockIdx.x * 256 + threadIdx.x;   // 0 .. 8191
    int lane = idx & 63;
    int ks   = (idx >> 6) & 3;
    int ot   = (idx >> 8) & 7;
    int b    = idx >> 11;

    int o  = ot * 16 + (lane & 15);
    int kb = ks * 32 + (lane >> 4) * 8;

    short8 v;
#pragma unroll
    for (int j = 0; j < 8; ++j)
        v[j] = (short)f2bf(V[((size_t)b * DIM + kb + j) * DIM + o]);
    *reinterpret_cast<short8*>(VfragG + (size_t)idx * 8) = v;
}

// ---------------------------------------------------------------------------
// W_r fragments (fallback path only)
// ---------------------------------------------------------------------------
__global__ __launch_bounds__(256) void build_wfrag(
    const float* __restrict__ A, const float* __restrict__ V,
    unsigned short* __restrict__ Wfrag)
{
    int idx  = blockIdx.x * 256 + threadIdx.x;   // 0 .. 16383
    int lane = idx & 63;
    int ks   = (idx >> 6) & 3;
    int ot   = (idx >> 8) & 7;
    int r    = idx >> 11;

    int o     = ot * 16 + (lane & 15);
    int kbase = ks * 32 + (lane >> 4) * 8;

    float a0 = A[r * NB + 0], a1 = A[r * NB + 1];
    float a2 = A[r * NB + 2], a3 = A[r * NB + 3];

    short8 v;
#pragma unroll
    for (int j = 0; j < 8; ++j) {
        int k = kbase + j;
        float w = a0 * V[(0 * DIM + k) * DIM + o]
                + a1 * V[(1 * DIM + k) * DIM + o]
                + a2 * V[(2 * DIM + k) * DIM + o]
                + a3 * V[(3 * DIM + k) * DIM + o];
        v[j] = (short)f2bf(w);
    }
    *reinterpret_cast<short8*>(Wfrag + (size_t)idx * 8) = v;
}

// ---------------------------------------------------------------------------
// H (fp32) -> Hbf (bf16), row-major [Ne][128]
// ---------------------------------------------------------------------------
__global__ __launch_bounds__(256) void h_to_bf(
    const float* __restrict__ H, unsigned short* __restrict__ Hbf, int n8)
{
    int i = blockIdx.x * 256 + threadIdx.x;
    if (i >= n8) return;
    const float4* hp = reinterpret_cast<const float4*>(H) + (size_t)i * 2;
    float4 f0 = hp[0];
    float4 f1 = hp[1];
    short8 v;
    v[0] = (short)f2bf(f0.x); v[1] = (short)f2bf(f0.y);
    v[2] = (short)f2bf(f0.z); v[3] = (short)f2bf(f0.w);
    v[4] = (short)f2bf(f1.x); v[5] = (short)f2bf(f1.y);
    v[6] = (short)f2bf(f1.z); v[7] = (short)f2bf(f1.w);
    *reinterpret_cast<short8*>(Hbf + (size_t)i * 8) = v;
}

// ---------------------------------------------------------------------------
// Counting sort of edges by destination row
// ---------------------------------------------------------------------------
__global__ __launch_bounds__(256) void hist_kernel(
    const int* __restrict__ erow, int* __restrict__ cnt, int n)
{
    int i = blockIdx.x * 256 + threadIdx.x;
    if (i < n) atomicAdd(cnt + erow[i], 1);
}

__global__ __launch_bounds__(256) void scan1(
    const int* __restrict__ cnt, int* __restrict__ rowStart,
    int* __restrict__ blockSums, int Ne)
{
    __shared__ int sd[256];
    int t = threadIdx.x, i = blockIdx.x * 256 + t;
    int c = (i < Ne) ? cnt[i] : 0;
    sd[t] = c; __syncthreads();
#pragma unroll
    for (int off = 1; off < 256; off <<= 1) {
        int v = (t >= off) ? sd[t - off] : 0;
        __syncthreads();
        sd[t] += v;
        __syncthreads();
    }
    if (i < Ne) rowStart[i] = sd[t] - c;
    if (t == 255) blockSums[blockIdx.x] = sd[t];
}

__global__ __launch_bounds__(512) void scan2(
    int* __restrict__ blockSums, int* __restrict__ rowStart, int nb, int Ne)
{
    __shared__ int sd[512];
    int t = threadIdx.x;
    int c = (t < nb) ? blockSums[t] : 0;
    sd[t] = c; __syncthreads();
#pragma unroll
    for (int off = 1; off < 512; off <<= 1) {
        int v = (t >= off) ? sd[t - off] : 0;
        __syncthreads();
        sd[t] += v;
        __syncthreads();
    }
    if (t < nb) blockSums[t] = sd[t] - c;
    if (t == nb - 1) rowStart[Ne] = sd[t];
}

__global__ __launch_bounds__(256) void scan3(
    int* __restrict__ rowStart, const int* __restrict__ blockSums, int Ne)
{
    int i = blockIdx.x * 256 + threadIdx.x;
    if (i < Ne) rowStart[i] += blockSums[blockIdx.x];
}

// scatter packed (key = r<<20 | col, val) records, 8 B per edge, one store
__global__ __launch_bounds__(256) void scatter2_kernel(
    const int* __restrict__ erow, const int* __restrict__ ecol,
    const float* __restrict__ eval, int* __restrict__ cursor,
    int2* __restrict__ sorted, int n, int E)
{
    int i = blockIdx.x * 256 + threadIdx.x;
    if (i >= n) return;
    int row = erow[i];
    int r   = (int)((unsigned)i / (unsigned)E);
    int2 m;
    m.x = (r << 20) | ecol[i];
    m.y = __float_as_int(eval[i]);
    int pos = atomicAdd(cursor + row, 1);
    sorted[pos] = m;
}

// ---------------------------------------------------------------------------
// K_A: basis aggregation. One wave per destination row.
// Agg[row][b*128 + i] = sum_{edges->row} val*A[r,b]*Hbf[col][i]   (bf16 out)
// Lane owns cols {2*lane, 2*lane+1}; 4 basis accumulators = 8 fp32 VGPRs.
// ---------------------------------------------------------------------------
__global__ __launch_bounds__(256) void agg_kernel(
    const unsigned short* __restrict__ Hbf,
    const int*  __restrict__ rowStart,
    const int2* __restrict__ sorted,
    const float* __restrict__ Aw,
    unsigned short* __restrict__ Agg, int Ne)
{
    __shared__ float4 ldsA[8];
    int tid = threadIdx.x;
    if (tid < 8) ldsA[tid] = reinterpret_cast<const float4*>(Aw)[tid];
    __syncthreads();

    int wid = blockIdx.x * 4 + (tid >> 6);
    if (wid >= Ne) return;
    int lane = tid & 63;

    int s = rowStart[wid], e = rowStart[wid + 1];

    float2 acc[4];
#pragma unroll
    for (int b = 0; b < 4; ++b) { acc[b].x = 0.f; acc[b].y = 0.f; }

    int i = s;
    for (; i + 4 <= e; i += 4) {
        int2 m0 = sorted[i],     m1 = sorted[i + 1];
        int2 m2 = sorted[i + 2], m3 = sorted[i + 3];
        unsigned int h0 = *reinterpret_cast<const unsigned int*>(
            Hbf + (size_t)(m0.x & 0xFFFFF) * DIM + lane * 2);
        unsigned int h1 = *reinterpret_cast<const unsigned int*>(
            Hbf + (size_t)(m1.x & 0xFFFFF) * DIM + lane * 2);
        unsigned int h2 = *reinterpret_cast<const unsigned int*>(
            Hbf + (size_t)(m2.x & 0xFFFFF) * DIM + lane * 2);
        unsigned int h3 = *reinterpret_cast<const unsigned int*>(
            Hbf + (size_t)(m3.x & 0xFFFFF) * DIM + lane * 2);

        int2 mm[4] = {m0, m1, m2, m3};
        unsigned int hh[4] = {h0, h1, h2, h3};
#pragma unroll
        for (int u = 0; u < 4; ++u) {
            float v = __int_as_float(mm[u].y);
            float4 a = ldsA[(unsigned)mm[u].x >> 20];
            float hx = bf_lo(hh[u]), hy = bf_hi(hh[u]);
            float s0 = v * a.x, s1 = v * a.y, s2 = v * a.z, s3 = v * a.w;
            acc[0].x += s0 * hx; acc[0].y += s0 * hy;
            acc[1].x += s1 * hx; acc[1].y += s1 * hy;
            acc[2].x += s2 * hx; acc[2].y += s2 * hy;
            acc[3].x += s3 * hx; acc[3].y += s3 * hy;
        }
    }
    for (; i < e; ++i) {
        int2 m = sorted[i];
        unsigned int h = *reinterpret_cast<const unsigned int*>(
            Hbf + (size_t)(m.x & 0xFFFFF) * DIM + lane * 2);
        float v = __int_as_float(m.y);
        float4 a = ldsA[(unsigned)m.x >> 20];
        float hx = bf_lo(h), hy = bf_hi(h);
        float s0 = v * a.x, s1 = v * a.y, s2 = v * a.z, s3 = v * a.w;
        acc[0].x += s0 * hx; acc[0].y += s0 * hy;
        acc[1].x += s1 * hx; acc[1].y += s1 * hy;
        acc[2].x += s2 * hx; acc[2].y += s2 * hy;
        acc[3].x += s3 * hx; acc[3].y += s3 * hy;
    }

    unsigned short* arow = Agg + (size_t)wid * 512 + lane * 2;
#pragma unroll
    for (int b = 0; b < 4; ++b) {
        unsigned int pk = (unsigned int)f2bf(acc[b].x)
                        | ((unsigned int)f2bf(acc[b].y) << 16);
        *reinterpret_cast<unsigned int*>(arow + b * 128) = pk;
    }
}

// ---------------------------------------------------------------------------
// K_B: out = Agg @ V  (M=Ne, K=512, N=128), MFMA.
// A-operand = V-frags from LDS (64 KB = one 64-col half), B-operand = Agg rows.
// D[o_local = quad*4+reg][node = lane&15]; out written exactly once.
// ---------------------------------------------------------------------------
__global__ __launch_bounds__(512) void vgemm_kernel(
    const unsigned short* __restrict__ Agg,
    const unsigned short* __restrict__ VfragG,
    float* __restrict__ out, int Ne, int nTiles)
{
    __shared__ short8 ldsV[4096];   // [b][otl][ks][lane], 64 KB
    int half = blockIdx.x & 1;
    int blk  = blockIdx.x >> 1;
    int nblk = gridDim.x >> 1;
    int tid  = threadIdx.x;

    for (int i = tid; i < 4096; i += 512) {
        int lane = i & 63, ks = (i >> 6) & 3, otl = (i >> 8) & 3, b = i >> 10;
        int gi = ((b * 8 + half * 4 + otl) * 4 + ks) * 64 + lane;
        ldsV[i] = reinterpret_cast<const short8*>(VfragG)[gi];
    }
    __syncthreads();

    int wave = tid >> 6;
    int lane = tid & 63;
    int quad = lane >> 4, l15 = lane & 15;

    int wgid = blk * 8 + wave;
    int nw   = nblk * 8;

    for (int tile = wgid; tile < nTiles; tile += nw) {
        int node0 = tile * 16;
        int node  = node0 + l15;
        int rdnode = node < Ne ? node : Ne - 1;

        const short8* bp = reinterpret_cast<const short8*>(Agg)
                         + (size_t)rdnode * 64 + quad;
        short8 bf[16];
#pragma unroll
        for (int b = 0; b < 4; ++b)
#pragma unroll
            for (int ks = 0; ks < 4; ++ks)
                bf[b * 4 + ks] = bp[b * 16 + ks * 4];

        floatx4 acc[4];
#pragma unroll
        for (int o = 0; o < 4; ++o) acc[o] = (floatx4){0.f, 0.f, 0.f, 0.f};

#pragma unroll
        for (int b = 0; b < 4; ++b)
#pragma unroll
            for (int ks = 0; ks < 4; ++ks)
#pragma unroll
                for (int otl = 0; otl < 4; ++otl)
                    acc[otl] = __builtin_amdgcn_mfma_f32_16x16x32_bf16(
                        ldsV[((b * 4 + otl) * 4 + ks) * 64 + lane],
                        bf[b * 4 + ks], acc[otl], 0, 0, 0);

        if (node < Ne) {
            float* orow = out + (size_t)node * DIM + half * 64;
#pragma unroll
            for (int otl = 0; otl < 4; ++otl) {
                float4 st;
                st.x = acc[otl][0]; st.y = acc[otl][1];
                st.z = acc[otl][2]; st.w = acc[otl][3];
                *reinterpret_cast<float4*>(orow + otl * 16 + quad * 4) = st;
            }
        }
    }
}

// ---------------------------------------------------------------------------
// Fallback (ws too small): round-2 atomic kernel
// ---------------------------------------------------------------------------
__global__ __launch_bounds__(256) void rgcn_main(
    const unsigned short* __restrict__ Hbf,
    const unsigned short* __restrict__ Wfrag,
    const int*   __restrict__ erow,
    const int*   __restrict__ ecol,
    const float* __restrict__ eval,
    float*       __restrict__ out,
    int E, int groups_per_rel, int waves_per_rel)
{
    int wid  = blockIdx.x * 4 + (threadIdx.x >> 6);
    int lane = threadIdx.x & 63;
    int r    = wid & 7;
    int wr   = wid >> 3;
    int quad = lane >> 4;
    int l15  = lane & 15;

    short8 b[8][4];
    {
        const short8* wp = reinterpret_cast<const short8*>(
            Wfrag + (size_t)r * 16384);
#pragma unroll
        for (int ot = 0; ot < 8; ++ot)
#pragma unroll
            for (int ks = 0; ks < 4; ++ks)
                b[ot][ks] = wp[(ot * 4 + ks) * 64 + lane];
    }

    for (int g = wr; g < groups_per_rel; g += waves_per_rel) {
        int ebase = r * E + g * 16;
        int   colv = ecol[ebase + l15];
        int   rowv = erow[ebase + l15];
        float valv = eval[ebase + l15];

        short8 a[4];
        const unsigned short* hp = Hbf + (size_t)colv * DIM + quad * 8;
#pragma unroll
        for (int ks = 0; ks < 4; ++ks)
            a[ks] = *reinterpret_cast<const short8*>(hp + ks * 32);

        floatx4 acc[8];
#pragma unroll
        for (int ot = 0; ot < 8; ++ot) acc[ot] = (floatx4){0.f, 0.f, 0.f, 0.f};
#pragma unroll
        for (int ot = 0; ot < 8; ++ot)
#pragma unroll
            for (int ks = 0; ks < 4; ++ks)
                acc[ot] = __builtin_amdgcn_mfma_f32_16x16x32_bf16(
                    a[ks], b[ot][ks], acc[ot], 0, 0, 0);

        int   row4[4];
        float val4[4];
#pragma unroll
        for (int reg = 0; reg < 4; ++reg) {
            int src  = quad * 4 + reg;
            row4[reg] = __shfl(rowv, src, 64);
            val4[reg] = __shfl(valv, src, 64);
        }
#pragma unroll
        for (int ot = 0; ot < 8; ++ot)
#pragma unroll
            for (int reg = 0; reg < 4; ++reg) {
                float m = acc[ot][reg] * val4[reg];
                atomicAdd(out + (size_t)row4[reg] * DIM + ot * 16 + l15, m);
            }
    }
}

extern "C" void kernel_launch(void* const* d_in, const int* in_sizes, int n_in,
                              void* d_out, int out_size, void* d_ws, size_t ws_size,
                              hipStream_t stream)
{
    const float* H    = (const float*)d_in[0];
    const float* A    = (const float*)d_in[1];
    const float* V    = (const float*)d_in[2];
    const int*   erow = (const int*)d_in[3];
    const int*   ecol = (const int*)d_in[4];
    const float* eval = (const float*)d_in[5];
    float* out = (float*)d_out;

    int Ne    = in_sizes[0] / DIM;   // 100000
    int NEtot = in_sizes[3];         // 1.6M
    int E     = NEtot / NR;          // 200000

    auto al = [](size_t x) { return (x + 255) & ~(size_t)255; };

    size_t offHbf   = 0;
    size_t offVfrag = offHbf   + al((size_t)Ne * DIM * 2);
    size_t offWfrag = offVfrag + al((size_t)8192 * 16);
    size_t offAgg   = offWfrag + al((size_t)16384 * 16);
    size_t offRow   = offAgg   + al((size_t)Ne * 512 * 2);
    size_t offCur   = offRow   + al(((size_t)Ne + 2) * 4);
    size_t offBS    = offCur   + al((size_t)Ne * 4);
    size_t offSort  = offBS    + al((size_t)512 * 4);
    size_t total    = offSort  + al((size_t)NEtot * 8);

    char* ws = (char*)d_ws;
    unsigned short* Hbf    = (unsigned short*)(ws + offHbf);
    unsigned short* VfragG = (unsigned short*)(ws + offVfrag);
    unsigned short* Wfrag  = (unsigned short*)(ws + offWfrag);

    int n8 = Ne * DIM / 8;
    h_to_bf<<<(n8 + 255) / 256, 256, 0, stream>>>(H, Hbf, n8);

    if (ws_size < total) {
        // fallback: atomic-scatter path (round 2)
        build_wfrag<<<64, 256, 0, stream>>>(A, V, Wfrag);
        hipMemsetAsync(d_out, 0, (size_t)Ne * DIM * sizeof(float), stream);
        int blocks = 4096;
        int waves_per_rel = blocks * 4 / NR;
        int groups_per_rel = E / 16;
        rgcn_main<<<blocks, 256, 0, stream>>>(Hbf, Wfrag, erow, ecol, eval, out,
                                              E, groups_per_rel, waves_per_rel);
        return;
    }

    unsigned short* Agg      = (unsigned short*)(ws + offAgg);
    int*            rowStart = (int*)(ws + offRow);
    int*            cursor   = (int*)(ws + offCur);
    int*            blockSums= (int*)(ws + offBS);
    int2*           sorted   = (int2*)(ws + offSort);

    build_vfrag<<<32, 256, 0, stream>>>(V, VfragG);

    // counting sort of edges by destination row
    hipMemsetAsync(cursor, 0, (size_t)Ne * 4, stream);
    hist_kernel<<<(NEtot + 255) / 256, 256, 0, stream>>>(erow, cursor, NEtot);

    int nb1 = (Ne + 255) / 256;   // 391 <= 512
    scan1<<<nb1, 256, 0, stream>>>(cursor, rowStart, blockSums, Ne);
    scan2<<<1, 512, 0, stream>>>(blockSums, rowStart, nb1, Ne);
    scan3<<<nb1, 256, 0, stream>>>(rowStart, blockSums, Ne);

    hipMemcpyAsync(cursor, rowStart, (size_t)Ne * 4,
                   hipMemcpyDeviceToDevice, stream);
    scatter2_kernel<<<(NEtot + 255) / 256, 256, 0, stream>>>(
        erow, ecol, eval, cursor, sorted, NEtot, E);

    // K_A: 4-basis aggregation (no atomics)
    agg_kernel<<<(Ne + 3) / 4, 256, 0, stream>>>(Hbf, rowStart, sorted, A,
                                                 Agg, Ne);

    // K_B: out = Agg @ V via MFMA, V-frags in LDS (two 64-col halves)
    int nTiles = (Ne + 15) / 16;   // 6250
    vgemm_kernel<<<512, 512, 0, stream>>>(Agg, VfragG, out, Ne, nTiles);
}

// Round 5
// 402.099 us; speedup vs baseline: 2.0101x; 1.1124x over previous
//
#include <hip/hip_runtime.h>

typedef __attribute__((ext_vector_type(8))) short short8;
typedef __attribute__((ext_vector_type(4))) float floatx4;

constexpr int DIM = 128;   // dim_in == dim_out
constexpr int NB  = 4;     // bases
constexpr int NR  = 8;     // relations
constexpr int BROWS = 512; // rows per sort bucket (localRow fits in 9+ bits)

static __device__ __forceinline__ unsigned short f2bf(float f) {
    unsigned int u = __float_as_uint(f);
    u += 0x7FFFu + ((u >> 16) & 1u);
    return (unsigned short)(u >> 16);
}
static __device__ __forceinline__ float bf_lo(unsigned int h) {
    return __uint_as_float(h << 16);
}
static __device__ __forceinline__ float bf_hi(unsigned int h) {
    return __uint_as_float(h & 0xFFFF0000u);
}

// ---------------------------------------------------------------------------
// Vfrag[b][ot][ks][lane][j] = V[b][k][o], k=ks*32+(lane>>4)*8+j, o=ot*16+(lane&15)
// ---------------------------------------------------------------------------
__global__ __launch_bounds__(256) void build_vfrag(
    const float* __restrict__ V, unsigned short* __restrict__ VfragG)
{
    int idx  = blockIdx.x * 256 + threadIdx.x;   // 0 .. 8191
    int lane = idx & 63;
    int ks   = (idx >> 6) & 3;
    int ot   = (idx >> 8) & 7;
    int b    = idx >> 11;

    int o  = ot * 16 + (lane & 15);
    int kb = ks * 32 + (lane >> 4) * 8;

    short8 v;
#pragma unroll
    for (int j = 0; j < 8; ++j)
        v[j] = (short)f2bf(V[((size_t)b * DIM + kb + j) * DIM + o]);
    *reinterpret_cast<short8*>(VfragG + (size_t)idx * 8) = v;
}

// ---------------------------------------------------------------------------
// W_r fragments (fallback path only)
// ---------------------------------------------------------------------------
__global__ __launch_bounds__(256) void build_wfrag(
    const float* __restrict__ A, const float* __restrict__ V,
    unsigned short* __restrict__ Wfrag)
{
    int idx  = blockIdx.x * 256 + threadIdx.x;   // 0 .. 16383
    int lane = idx & 63;
    int ks   = (idx >> 6) & 3;
    int ot   = (idx >> 8) & 7;
    int r    = idx >> 11;

    int o     = ot * 16 + (lane & 15);
    int kbase = ks * 32 + (lane >> 4) * 8;

    float a0 = A[r * NB + 0], a1 = A[r * NB + 1];
    float a2 = A[r * NB + 2], a3 = A[r * NB + 3];

    short8 v;
#pragma unroll
    for (int j = 0; j < 8; ++j) {
        int k = kbase + j;
        float w = a0 * V[(0 * DIM + k) * DIM + o]
                + a1 * V[(1 * DIM + k) * DIM + o]
                + a2 * V[(2 * DIM + k) * DIM + o]
                + a3 * V[(3 * DIM + k) * DIM + o];
        v[j] = (short)f2bf(w);
    }
    *reinterpret_cast<short8*>(Wfrag + (size_t)idx * 8) = v;
}

// ---------------------------------------------------------------------------
// H (fp32) -> Hbf (bf16), row-major [Ne][128]
// ---------------------------------------------------------------------------
__global__ __launch_bounds__(256) void h_to_bf(
    const float* __restrict__ H, unsigned short* __restrict__ Hbf, int n8)
{
    int i = blockIdx.x * 256 + threadIdx.x;
    if (i >= n8) return;
    const float4* hp = reinterpret_cast<const float4*>(H) + (size_t)i * 2;
    float4 f0 = hp[0];
    float4 f1 = hp[1];
    short8 v;
    v[0] = (short)f2bf(f0.x); v[1] = (short)f2bf(f0.y);
    v[2] = (short)f2bf(f0.z); v[3] = (short)f2bf(f0.w);
    v[4] = (short)f2bf(f1.x); v[5] = (short)f2bf(f1.y);
    v[6] = (short)f2bf(f1.z); v[7] = (short)f2bf(f1.w);
    *reinterpret_cast<short8*>(Hbf + (size_t)i * 8) = v;
}

// ---------------------------------------------------------------------------
// Counting sort scaffolding: per-row histogram + scan -> rowStart[Ne+1]
// ---------------------------------------------------------------------------
__global__ __launch_bounds__(256) void hist_kernel(
    const int* __restrict__ erow, int* __restrict__ cnt, int n)
{
    int i = blockIdx.x * 256 + threadIdx.x;
    if (i < n) atomicAdd(cnt + erow[i], 1);
}

__global__ __launch_bounds__(256) void scan1(
    const int* __restrict__ cnt, int* __restrict__ rowStart,
    int* __restrict__ blockSums, int Ne)
{
    __shared__ int sd[256];
    int t = threadIdx.x, i = blockIdx.x * 256 + t;
    int c = (i < Ne) ? cnt[i] : 0;
    sd[t] = c; __syncthreads();
#pragma unroll
    for (int off = 1; off < 256; off <<= 1) {
        int v = (t >= off) ? sd[t - off] : 0;
        __syncthreads();
        sd[t] += v;
        __syncthreads();
    }
    if (i < Ne) rowStart[i] = sd[t] - c;
    if (t == 255) blockSums[blockIdx.x] = sd[t];
}

__global__ __launch_bounds__(512) void scan2(
    int* __restrict__ blockSums, int* __restrict__ rowStart, int nb, int Ne)
{
    __shared__ int sd[512];
    int t = threadIdx.x;
    int c = (t < nb) ? blockSums[t] : 0;
    sd[t] = c; __syncthreads();
#pragma unroll
    for (int off = 1; off < 512; off <<= 1) {
        int v = (t >= off) ? sd[t - off] : 0;
        __syncthreads();
        sd[t] += v;
        __syncthreads();
    }
    if (t < nb) blockSums[t] = sd[t] - c;
    if (t == nb - 1) rowStart[Ne] = sd[t];
}

__global__ __launch_bounds__(256) void scan3(
    int* __restrict__ rowStart, const int* __restrict__ blockSums, int Ne)
{
    int i = blockIdx.x * 256 + threadIdx.x;
    if (i < Ne) rowStart[i] += blockSums[blockIdx.x];
}

// bcur[b] = rowStart[b*BROWS]  (bucket write cursors for pass 1)
__global__ __launch_bounds__(256) void init_bcur(
    const int* __restrict__ rowStart, int* __restrict__ bcur, int nbuc, int Ne)
{
    int b = blockIdx.x * 256 + threadIdx.x;
    if (b < nbuc) {
        int r = b * BROWS;
        bcur[b] = rowStart[r < Ne ? r : Ne];
    }
}

// ---------------------------------------------------------------------------
// Sort pass 1: scatter edges into coarse buckets (bucket = row >> 9).
// Per-block LDS histogram -> one global atomicAdd per (block,bucket) ->
// contiguous runs per bucket (low write amplification).
// Record: key = localRow<<20 | r<<17 | col  (9+ | 3 | 17 bits), val fp32.
// ---------------------------------------------------------------------------
__global__ __launch_bounds__(256) void bucket_scatter(
    const int* __restrict__ erow, const int* __restrict__ ecol,
    const float* __restrict__ eval, int* __restrict__ bcur,
    int2* __restrict__ sorted1, int n, int E, int chunk)
{
    __shared__ int cnt[256];
    __shared__ int base[256];
    int t = threadIdx.x;
    cnt[t] = 0;
    __syncthreads();

    int s = blockIdx.x * chunk;
    int e = s + chunk; if (e > n) e = n;

    // sweep A: per-bucket count
    for (int i = s + t; i < e; i += 256)
        atomicAdd(&cnt[erow[i] >> 9], 1);
    __syncthreads();

    int c = cnt[t];
    base[t] = (c > 0) ? atomicAdd(&bcur[t], c) : 0;
    cnt[t] = 0;
    __syncthreads();

    // sweep B: scatter into reserved runs
    for (int i = s + t; i < e; i += 256) {
        int row = erow[i];
        int bkt = row >> 9;
        int rank = atomicAdd(&cnt[bkt], 1);
        int r = (int)((unsigned)i / (unsigned)E);
        int2 m;
        m.x = ((row & (BROWS - 1)) << 20) | (r << 17) | ecol[i];
        m.y = __float_as_int(eval[i]);
        sorted1[base[bkt] + rank] = m;
    }
}

// ---------------------------------------------------------------------------
// Sort pass 2: one block per bucket. Bucket's records are contiguous
// (coalesced read); exact position via rowStart + LDS per-row rank.
// Writes land within the bucket's ~64KB output window (L2-absorbed).
// ---------------------------------------------------------------------------
__global__ __launch_bounds__(256) void bucket_sort(
    const int2* __restrict__ sorted1, const int* __restrict__ rowStart,
    int2* __restrict__ sorted, int Ne)
{
    __shared__ int cnt[BROWS];
    int b = blockIdx.x;
    int t = threadIdx.x;
    cnt[t] = 0; cnt[t + 256] = 0;
    __syncthreads();

    int rs = b * BROWS;
    int re = rs + BROWS; if (re > Ne) re = Ne;
    int s = rowStart[rs];
    int e = rowStart[re];
    const int* rsBase = rowStart + rs;

    for (int i = s + t; i < e; i += 256) {
        int2 m = sorted1[i];
        int lr = (unsigned)m.x >> 20;
        int pos = rsBase[lr] + atomicAdd(&cnt[lr], 1);
        sorted[pos] = m;
    }
}

// ---------------------------------------------------------------------------
// K_A: basis aggregation. One wave per destination row.
// Agg[row][b*128 + i] = sum_{edges->row} val*A[r,b]*Hbf[col][i]   (bf16 out)
// key: col = m.x & 0x1FFFF, r = (m.x >> 17) & 7
// ---------------------------------------------------------------------------
__global__ __launch_bounds__(256) void agg_kernel(
    const unsigned short* __restrict__ Hbf,
    const int*  __restrict__ rowStart,
    const int2* __restrict__ sorted,
    const float* __restrict__ Aw,
    unsigned short* __restrict__ Agg, int Ne)
{
    __shared__ float4 ldsA[8];
    int tid = threadIdx.x;
    if (tid < 8) ldsA[tid] = reinterpret_cast<const float4*>(Aw)[tid];
    __syncthreads();

    int wid = blockIdx.x * 4 + (tid >> 6);
    if (wid >= Ne) return;
    int lane = tid & 63;

    int s = rowStart[wid], e = rowStart[wid + 1];

    float2 acc[4];
#pragma unroll
    for (int b = 0; b < 4; ++b) { acc[b].x = 0.f; acc[b].y = 0.f; }

    int i = s;
    for (; i + 4 <= e; i += 4) {
        int2 m0 = sorted[i],     m1 = sorted[i + 1];
        int2 m2 = sorted[i + 2], m3 = sorted[i + 3];
        unsigned int h0 = *reinterpret_cast<const unsigned int*>(
            Hbf + (size_t)(m0.x & 0x1FFFF) * DIM + lane * 2);
        unsigned int h1 = *reinterpret_cast<const unsigned int*>(
            Hbf + (size_t)(m1.x & 0x1FFFF) * DIM + lane * 2);
        unsigned int h2 = *reinterpret_cast<const unsigned int*>(
            Hbf + (size_t)(m2.x & 0x1FFFF) * DIM + lane * 2);
        unsigned int h3 = *reinterpret_cast<const unsigned int*>(
            Hbf + (size_t)(m3.x & 0x1FFFF) * DIM + lane * 2);

        int2 mm[4] = {m0, m1, m2, m3};
        unsigned int hh[4] = {h0, h1, h2, h3};
#pragma unroll
        for (int u = 0; u < 4; ++u) {
            float v = __int_as_float(mm[u].y);
            float4 a = ldsA[((unsigned)mm[u].x >> 17) & 7];
            float hx = bf_lo(hh[u]), hy = bf_hi(hh[u]);
            float s0 = v * a.x, s1 = v * a.y, s2 = v * a.z, s3 = v * a.w;
            acc[0].x += s0 * hx; acc[0].y += s0 * hy;
            acc[1].x += s1 * hx; acc[1].y += s1 * hy;
            acc[2].x += s2 * hx; acc[2].y += s2 * hy;
            acc[3].x += s3 * hx; acc[3].y += s3 * hy;
        }
    }
    for (; i < e; ++i) {
        int2 m = sorted[i];
        unsigned int h = *reinterpret_cast<const unsigned int*>(
            Hbf + (size_t)(m.x & 0x1FFFF) * DIM + lane * 2);
        float v = __int_as_float(m.y);
        float4 a = ldsA[((unsigned)m.x >> 17) & 7];
        float hx = bf_lo(h), hy = bf_hi(h);
        float s0 = v * a.x, s1 = v * a.y, s2 = v * a.z, s3 = v * a.w;
        acc[0].x += s0 * hx; acc[0].y += s0 * hy;
        acc[1].x += s1 * hx; acc[1].y += s1 * hy;
        acc[2].x += s2 * hx; acc[2].y += s2 * hy;
        acc[3].x += s3 * hx; acc[3].y += s3 * hy;
    }

    unsigned short* arow = Agg + (size_t)wid * 512 + lane * 2;
#pragma unroll
    for (int b = 0; b < 4; ++b) {
        unsigned int pk = (unsigned int)f2bf(acc[b].x)
                        | ((unsigned int)f2bf(acc[b].y) << 16);
        *reinterpret_cast<unsigned int*>(arow + b * 128) = pk;
    }
}

// ---------------------------------------------------------------------------
// K_B: out = Agg @ V  (M=Ne, K=512, N=128), MFMA.
// ---------------------------------------------------------------------------
__global__ __launch_bounds__(512) void vgemm_kernel(
    const unsigned short* __restrict__ Agg,
    const unsigned short* __restrict__ VfragG,
    float* __restrict__ out, int Ne, int nTiles)
{
    __shared__ short8 ldsV[4096];   // [b][otl][ks][lane], 64 KB
    int half = blockIdx.x & 1;
    int blk  = blockIdx.x >> 1;
    int nblk = gridDim.x >> 1;
    int tid  = threadIdx.x;

    for (int i = tid; i < 4096; i += 512) {
        int lane = i & 63, ks = (i >> 6) & 3, otl = (i >> 8) & 3, b = i >> 10;
        int gi = ((b * 8 + half * 4 + otl) * 4 + ks) * 64 + lane;
        ldsV[i] = reinterpret_cast<const short8*>(VfragG)[gi];
    }
    __syncthreads();

    int wave = tid >> 6;
    int lane = tid & 63;
    int quad = lane >> 4, l15 = lane & 15;

    int wgid = blk * 8 + wave;
    int nw   = nblk * 8;

    for (int tile = wgid; tile < nTiles; tile += nw) {
        int node0 = tile * 16;
        int node  = node0 + l15;
        int rdnode = node < Ne ? node : Ne - 1;

        const short8* bp = reinterpret_cast<const short8*>(Agg)
                         + (size_t)rdnode * 64 + quad;
        short8 bf[16];
#pragma unroll
        for (int b = 0; b < 4; ++b)
#pragma unroll
            for (int ks = 0; ks < 4; ++ks)
                bf[b * 4 + ks] = bp[b * 16 + ks * 4];

        floatx4 acc[4];
#pragma unroll
        for (int o = 0; o < 4; ++o) acc[o] = (floatx4){0.f, 0.f, 0.f, 0.f};

#pragma unroll
        for (int b = 0; b < 4; ++b)
#pragma unroll
            for (int ks = 0; ks < 4; ++ks)
#pragma unroll
                for (int otl = 0; otl < 4; ++otl)
                    acc[otl] = __builtin_amdgcn_mfma_f32_16x16x32_bf16(
                        ldsV[((b * 4 + otl) * 4 + ks) * 64 + lane],
                        bf[b * 4 + ks], acc[otl], 0, 0, 0);

        if (node < Ne) {
            float* orow = out + (size_t)node * DIM + half * 64;
#pragma unroll
            for (int otl = 0; otl < 4; ++otl) {
                float4 st;
                st.x = acc[otl][0]; st.y = acc[otl][1];
                st.z = acc[otl][2]; st.w = acc[otl][3];
                *reinterpret_cast<float4*>(orow + otl * 16 + quad * 4) = st;
            }
        }
    }
}

// ---------------------------------------------------------------------------
// Fallback (ws too small): round-2 atomic kernel
// ---------------------------------------------------------------------------
__global__ __launch_bounds__(256) void rgcn_main(
    const unsigned short* __restrict__ Hbf,
    const unsigned short* __restrict__ Wfrag,
    const int*   __restrict__ erow,
    const int*   __restrict__ ecol,
    const float* __restrict__ eval,
    float*       __restrict__ out,
    int E, int groups_per_rel, int waves_per_rel)
{
    int wid  = blockIdx.x * 4 + (threadIdx.x >> 6);
    int lane = threadIdx.x & 63;
    int r    = wid & 7;
    int wr   = wid >> 3;
    int quad = lane >> 4;
    int l15  = lane & 15;

    short8 b[8][4];
    {
        const short8* wp = reinterpret_cast<const short8*>(
            Wfrag + (size_t)r * 16384);
#pragma unroll
        for (int ot = 0; ot < 8; ++ot)
#pragma unroll
            for (int ks = 0; ks < 4; ++ks)
                b[ot][ks] = wp[(ot * 4 + ks) * 64 + lane];
    }

    for (int g = wr; g < groups_per_rel; g += waves_per_rel) {
        int ebase = r * E + g * 16;
        int   colv = ecol[ebase + l15];
        int   rowv = erow[ebase + l15];
        float valv = eval[ebase + l15];

        short8 a[4];
        const unsigned short* hp = Hbf + (size_t)colv * DIM + quad * 8;
#pragma unroll
        for (int ks = 0; ks < 4; ++ks)
            a[ks] = *reinterpret_cast<const short8*>(hp + ks * 32);

        floatx4 acc[8];
#pragma unroll
        for (int ot = 0; ot < 8; ++ot) acc[ot] = (floatx4){0.f, 0.f, 0.f, 0.f};
#pragma unroll
        for (int ot = 0; ot < 8; ++ot)
#pragma unroll
            for (int ks = 0; ks < 4; ++ks)
                acc[ot] = __builtin_amdgcn_mfma_f32_16x16x32_bf16(
                    a[ks], b[ot][ks], acc[ot], 0, 0, 0);

        int   row4[4];
        float val4[4];
#pragma unroll
        for (int reg = 0; reg < 4; ++reg) {
            int src  = quad * 4 + reg;
            row4[reg] = __shfl(rowv, src, 64);
            val4[reg] = __shfl(valv, src, 64);
        }
#pragma unroll
        for (int ot = 0; ot < 8; ++ot)
#pragma unroll
            for (int reg = 0; reg < 4; ++reg) {
                float m = acc[ot][reg] * val4[reg];
                atomicAdd(out + (size_t)row4[reg] * DIM + ot * 16 + l15, m);
            }
    }
}

extern "C" void kernel_launch(void* const* d_in, const int* in_sizes, int n_in,
                              void* d_out, int out_size, void* d_ws, size_t ws_size,
                              hipStream_t stream)
{
    const float* H    = (const float*)d_in[0];
    const float* A    = (const float*)d_in[1];
    const float* V    = (const float*)d_in[2];
    const int*   erow = (const int*)d_in[3];
    const int*   ecol = (const int*)d_in[4];
    const float* eval = (const float*)d_in[5];
    float* out = (float*)d_out;

    int Ne    = in_sizes[0] / DIM;   // 100000
    int NEtot = in_sizes[3];         // 1.6M
    int E     = NEtot / NR;          // 200000

    auto al = [](size_t x) { return (x + 255) & ~(size_t)255; };

    size_t offHbf   = 0;
    size_t offVfrag = offHbf   + al((size_t)Ne * DIM * 2);
    size_t offWfrag = offVfrag + al((size_t)8192 * 16);
    size_t offAgg   = offWfrag + al((size_t)16384 * 16);
    size_t offRow   = offAgg   + al((size_t)Ne * 512 * 2);
    size_t offCur   = offRow   + al(((size_t)Ne + 2) * 4);
    size_t offBS    = offCur   + al((size_t)Ne * 4);
    size_t offBcur  = offBS    + al((size_t)512 * 4);
    size_t offSort1 = offBcur  + al((size_t)256 * 4);
    size_t offSort  = offSort1 + al((size_t)NEtot * 8);
    size_t total    = offSort  + al((size_t)NEtot * 8);

    char* ws = (char*)d_ws;
    unsigned short* Hbf    = (unsigned short*)(ws + offHbf);
    unsigned short* VfragG = (unsigned short*)(ws + offVfrag);
    unsigned short* Wfrag  = (unsigned short*)(ws + offWfrag);

    int n8 = Ne * DIM / 8;
    h_to_bf<<<(n8 + 255) / 256, 256, 0, stream>>>(H, Hbf, n8);

    if (ws_size < total) {
        // fallback: atomic-scatter path (round 2)
        build_wfrag<<<64, 256, 0, stream>>>(A, V, Wfrag);
        hipMemsetAsync(d_out, 0, (size_t)Ne * DIM * sizeof(float), stream);
        int blocks = 4096;
        int waves_per_rel = blocks * 4 / NR;
        int groups_per_rel = E / 16;
        rgcn_main<<<blocks, 256, 0, stream>>>(Hbf, Wfrag, erow, ecol, eval, out,
                                              E, groups_per_rel, waves_per_rel);
        return;
    }

    unsigned short* Agg      = (unsigned short*)(ws + offAgg);
    int*            rowStart = (int*)(ws + offRow);
    int*            cursor   = (int*)(ws + offCur);
    int*            blockSums= (int*)(ws + offBS);
    int*            bcur     = (int*)(ws + offBcur);
    int2*           sorted1  = (int2*)(ws + offSort1);
    int2*           sorted   = (int2*)(ws + offSort);

    build_vfrag<<<32, 256, 0, stream>>>(V, VfragG);

    // per-row histogram + scan -> rowStart
    hipMemsetAsync(cursor, 0, (size_t)Ne * 4, stream);
    hist_kernel<<<(NEtot + 255) / 256, 256, 0, stream>>>(erow, cursor, NEtot);

    int nb1 = (Ne + 255) / 256;   // 391 <= 512
    scan1<<<nb1, 256, 0, stream>>>(cursor, rowStart, blockSums, Ne);
    scan2<<<1, 512, 0, stream>>>(blockSums, rowStart, nb1, Ne);
    scan3<<<nb1, 256, 0, stream>>>(rowStart, blockSums, Ne);

    // two-level bucket sort (replaces the random global scatter)
    int nbuc = (Ne + BROWS - 1) / BROWS;   // 196
    init_bcur<<<1, 256, 0, stream>>>(rowStart, bcur, nbuc, Ne);

    int sblocks = 512;
    int chunk   = (NEtot + sblocks - 1) / sblocks;   // 3125
    bucket_scatter<<<sblocks, 256, 0, stream>>>(erow, ecol, eval, bcur,
                                                sorted1, NEtot, E, chunk);
    bucket_sort<<<nbuc, 256, 0, stream>>>(sorted1, rowStart, sorted, Ne);

    // K_A: 4-basis aggregation (no atomics)
    agg_kernel<<<(Ne + 3) / 4, 256, 0, stream>>>(Hbf, rowStart, sorted, A,
                                                 Agg, Ne);

    // K_B: out = Agg @ V via MFMA, V-frags in LDS (two 64-col halves)
    int nTiles = (Ne + 15) / 16;   // 6250
    vgemm_kernel<<<512, 512, 0, stream>>>(Agg, VfragG, out, Ne, nTiles);
}

// Round 6
// 332.778 us; speedup vs baseline: 2.4289x; 1.2083x over previous
//
#include <hip/hip_runtime.h>

typedef __attribute__((ext_vector_type(8))) short short8;
typedef __attribute__((ext_vector_type(4))) float floatx4;

constexpr int DIM   = 128;   // dim_in == dim_out
constexpr int NB    = 4;     // bases
constexpr int NR    = 8;     // relations
constexpr int BROWS = 512;   // rows per sort bucket
constexpr int BCAP  = 16384; // fixed bucket capacity (mean 8192, +90 sigma)

static __device__ __forceinline__ unsigned short f2bf(float f) {
    unsigned int u = __float_as_uint(f);
    u += 0x7FFFu + ((u >> 16) & 1u);
    return (unsigned short)(u >> 16);
}
static __device__ __forceinline__ float bf_lo(unsigned int h) {
    return __uint_as_float(h << 16);
}
static __device__ __forceinline__ float bf_hi(unsigned int h) {
    return __uint_as_float(h & 0xFFFF0000u);
}

// ---------------------------------------------------------------------------
// Vfrag[b][ot][ks][lane][j] = V[b][k][o], k=ks*32+(lane>>4)*8+j, o=ot*16+(lane&15)
// ---------------------------------------------------------------------------
__global__ __launch_bounds__(256) void build_vfrag(
    const float* __restrict__ V, unsigned short* __restrict__ VfragG)
{
    int idx  = blockIdx.x * 256 + threadIdx.x;   // 0 .. 8191
    int lane = idx & 63;
    int ks   = (idx >> 6) & 3;
    int ot   = (idx >> 8) & 7;
    int b    = idx >> 11;

    int o  = ot * 16 + (lane & 15);
    int kb = ks * 32 + (lane >> 4) * 8;

    short8 v;
#pragma unroll
    for (int j = 0; j < 8; ++j)
        v[j] = (short)f2bf(V[((size_t)b * DIM + kb + j) * DIM + o]);
    *reinterpret_cast<short8*>(VfragG + (size_t)idx * 8) = v;
}

// ---------------------------------------------------------------------------
// W_r fragments (fallback path only)
// ---------------------------------------------------------------------------
__global__ __launch_bounds__(256) void build_wfrag(
    const float* __restrict__ A, const float* __restrict__ V,
    unsigned short* __restrict__ Wfrag)
{
    int idx  = blockIdx.x * 256 + threadIdx.x;   // 0 .. 16383
    int lane = idx & 63;
    int ks   = (idx >> 6) & 3;
    int ot   = (idx >> 8) & 7;
    int r    = idx >> 11;

    int o     = ot * 16 + (lane & 15);
    int kbase = ks * 32 + (lane >> 4) * 8;

    float a0 = A[r * NB + 0], a1 = A[r * NB + 1];
    float a2 = A[r * NB + 2], a3 = A[r * NB + 3];

    short8 v;
#pragma unroll
    for (int j = 0; j < 8; ++j) {
        int k = kbase + j;
        float w = a0 * V[(0 * DIM + k) * DIM + o]
                + a1 * V[(1 * DIM + k) * DIM + o]
                + a2 * V[(2 * DIM + k) * DIM + o]
                + a3 * V[(3 * DIM + k) * DIM + o];
        v[j] = (short)f2bf(w);
    }
    *reinterpret_cast<short8*>(Wfrag + (size_t)idx * 8) = v;
}

// ---------------------------------------------------------------------------
// H (fp32) -> Hbf (bf16), row-major [Ne][128]
// ---------------------------------------------------------------------------
__global__ __launch_bounds__(256) void h_to_bf(
    const float* __restrict__ H, unsigned short* __restrict__ Hbf, int n8)
{
    int i = blockIdx.x * 256 + threadIdx.x;
    if (i >= n8) return;
    const float4* hp = reinterpret_cast<const float4*>(H) + (size_t)i * 2;
    float4 f0 = hp[0];
    float4 f1 = hp[1];
    short8 v;
    v[0] = (short)f2bf(f0.x); v[1] = (short)f2bf(f0.y);
    v[2] = (short)f2bf(f0.z); v[3] = (short)f2bf(f0.w);
    v[4] = (short)f2bf(f1.x); v[5] = (short)f2bf(f1.y);
    v[6] = (short)f2bf(f1.z); v[7] = (short)f2bf(f1.w);
    *reinterpret_cast<short8*>(Hbf + (size_t)i * 8) = v;
}

// ---------------------------------------------------------------------------
// Sort pass 1: scatter edges into fixed-capacity coarse buckets
// (bucket = row >> 9). Per-block LDS histogram -> one global atomicAdd per
// (block,bucket) -> contiguous runs. No rowStart dependency.
// Record: key = localRow<<20 | r<<17 | col  (9 | 3 | 17 bits), val fp32.
// ---------------------------------------------------------------------------
__global__ __launch_bounds__(256) void bucket_scatter(
    const int* __restrict__ erow, const int* __restrict__ ecol,
    const float* __restrict__ eval, int* __restrict__ bcnt,
    int2* __restrict__ sorted1, int n, int E, int chunk)
{
    __shared__ int cnt[256];
    __shared__ int base[256];
    int t = threadIdx.x;
    cnt[t] = 0;
    __syncthreads();

    int s = blockIdx.x * chunk;
    int e = s + chunk; if (e > n) e = n;

    for (int i = s + t; i < e; i += 256)
        atomicAdd(&cnt[erow[i] >> 9], 1);
    __syncthreads();

    int c = cnt[t];
    base[t] = (c > 0) ? atomicAdd(&bcnt[t], c) : 0;
    cnt[t] = 0;
    __syncthreads();

    for (int i = s + t; i < e; i += 256) {
        int row = erow[i];
        int bkt = row >> 9;
        int rank = atomicAdd(&cnt[bkt], 1);
        int r = (int)((unsigned)i / (unsigned)E);
        int2 m;
        m.x = ((row & (BROWS - 1)) << 20) | (r << 17) | ecol[i];
        m.y = __float_as_int(eval[i]);
        sorted1[(size_t)bkt * BCAP + base[bkt] + rank] = m;
    }
}

// ---------------------------------------------------------------------------
// Exclusive scan over the 196 bucket counts (single block); also finalize
// rowStart[Ne] = total edge count.
// ---------------------------------------------------------------------------
__global__ __launch_bounds__(256) void bucket_scan(
    const int* __restrict__ bcnt, int* __restrict__ bstart,
    int* __restrict__ rowStart, int nbuc, int Ne)
{
    __shared__ int sd[256];
    int t = threadIdx.x;
    int c = (t < nbuc) ? bcnt[t] : 0;
    sd[t] = c; __syncthreads();
#pragma unroll
    for (int off = 1; off < 256; off <<= 1) {
        int v = (t >= off) ? sd[t - off] : 0;
        __syncthreads();
        sd[t] += v;
        __syncthreads();
    }
    if (t < nbuc) bstart[t] = sd[t] - c;
    if (t == nbuc - 1) rowStart[Ne] = sd[t];
}

// ---------------------------------------------------------------------------
// Sort pass 2: one block per bucket. Contiguous read of the bucket's
// records; per-row LDS histogram + scan -> emits rowStart for its 512 rows
// and compacts records to exact final positions (writes land in the
// bucket's ~128KB output window -> L2-absorbed).
// ---------------------------------------------------------------------------
__global__ __launch_bounds__(256) void bucket_sort(
    const int2* __restrict__ sorted1, const int* __restrict__ bcnt,
    const int* __restrict__ bstart, int* __restrict__ rowStart,
    int2* __restrict__ sorted, int Ne)
{
    __shared__ int hcnt[BROWS];
    __shared__ int hoff[BROWS];
    int b = blockIdx.x;
    int t = threadIdx.x;
    hcnt[t] = 0; hcnt[t + 256] = 0;
    __syncthreads();

    int n = bcnt[b];
    const int2* src = sorted1 + (size_t)b * BCAP;

    for (int i = t; i < n; i += 256)
        atomicAdd(&hcnt[(unsigned)src[i].x >> 20], 1);
    __syncthreads();

    if (t == 0) {
        int run = 0;
#pragma unroll 8
        for (int j = 0; j < BROWS; ++j) { hoff[j] = run; run += hcnt[j]; }
    }
    __syncthreads();

    int bs = bstart[b];
    int rs = b * BROWS;
    int nr = Ne - rs; if (nr > BROWS) nr = BROWS;
    for (int j = t; j < nr; j += 256)
        rowStart[rs + j] = bs + hoff[j];

    hcnt[t] = 0; hcnt[t + 256] = 0;
    __syncthreads();

    for (int i = t; i < n; i += 256) {
        int2 m = src[i];
        int lr = (unsigned)m.x >> 20;
        int pos = bs + hoff[lr] + atomicAdd(&hcnt[lr], 1);
        sorted[pos] = m;
    }
}

// ---------------------------------------------------------------------------
// K_A: basis aggregation. One wave per destination row.
// Agg[row][b*128 + i] = sum_{edges->row} val*A[r,b]*Hbf[col][i]   (bf16 out)
// Per-edge control (record decode, A[r] fetch, gather base) is scalarized
// via readfirstlane -> s_load + SGPR-base gathers; VALU does only the FMAs.
// ---------------------------------------------------------------------------
__global__ __launch_bounds__(256) void agg_kernel(
    const unsigned short* __restrict__ Hbf,
    const int*  __restrict__ rowStart,
    const int2* __restrict__ sorted,
    const float* __restrict__ Aw,
    unsigned short* __restrict__ Agg, int Ne)
{
    int tid  = threadIdx.x;
    int wid  = __builtin_amdgcn_readfirstlane(blockIdx.x * 4 + (tid >> 6));
    if (wid >= Ne) return;
    int lane = tid & 63;

    int s = __builtin_amdgcn_readfirstlane(rowStart[wid]);
    int e = __builtin_amdgcn_readfirstlane(rowStart[wid + 1]);

    const float4* Af = reinterpret_cast<const float4*>(Aw);

    float2 acc[4];
#pragma unroll
    for (int b = 0; b < 4; ++b) { acc[b].x = 0.f; acc[b].y = 0.f; }

    int i = s;
    for (; i + 4 <= e; i += 4) {
        int2 m0 = sorted[i],     m1 = sorted[i + 1];
        int2 m2 = sorted[i + 2], m3 = sorted[i + 3];
        int k0 = __builtin_amdgcn_readfirstlane(m0.x);
        int k1 = __builtin_amdgcn_readfirstlane(m1.x);
        int k2 = __builtin_amdgcn_readfirstlane(m2.x);
        int k3 = __builtin_amdgcn_readfirstlane(m3.x);
        float v0 = __uint_as_float(__builtin_amdgcn_readfirstlane(m0.y));
        float v1 = __uint_as_float(__builtin_amdgcn_readfirstlane(m1.y));
        float v2 = __uint_as_float(__builtin_amdgcn_readfirstlane(m2.y));
        float v3 = __uint_as_float(__builtin_amdgcn_readfirstlane(m3.y));

        unsigned int h0 = reinterpret_cast<const unsigned int*>(
            Hbf + (size_t)(k0 & 0x1FFFF) * DIM)[lane];
        unsigned int h1 = reinterpret_cast<const unsigned int*>(
            Hbf + (size_t)(k1 & 0x1FFFF) * DIM)[lane];
        unsigned int h2 = reinterpret_cast<const unsigned int*>(
            Hbf + (size_t)(k2 & 0x1FFFF) * DIM)[lane];
        unsigned int h3 = reinterpret_cast<const unsigned int*>(
            Hbf + (size_t)(k3 & 0x1FFFF) * DIM)[lane];

        int kk[4] = {k0, k1, k2, k3};
        float vv[4] = {v0, v1, v2, v3};
        unsigned int hh[4] = {h0, h1, h2, h3};
#pragma unroll
        for (int u = 0; u < 4; ++u) {
            float4 a = Af[((unsigned)kk[u] >> 17) & 7];
            float hx = bf_lo(hh[u]), hy = bf_hi(hh[u]);
            float s0 = vv[u] * a.x, s1 = vv[u] * a.y;
            float s2 = vv[u] * a.z, s3 = vv[u] * a.w;
            acc[0].x += s0 * hx; acc[0].y += s0 * hy;
            acc[1].x += s1 * hx; acc[1].y += s1 * hy;
            acc[2].x += s2 * hx; acc[2].y += s2 * hy;
            acc[3].x += s3 * hx; acc[3].y += s3 * hy;
        }
    }
    for (; i < e; ++i) {
        int2 m = sorted[i];
        int k = __builtin_amdgcn_readfirstlane(m.x);
        float v = __uint_as_float(__builtin_amdgcn_readfirstlane(m.y));
        unsigned int h = reinterpret_cast<const unsigned int*>(
            Hbf + (size_t)(k & 0x1FFFF) * DIM)[lane];
        float4 a = Af[((unsigned)k >> 17) & 7];
        float hx = bf_lo(h), hy = bf_hi(h);
        float s0 = v * a.x, s1 = v * a.y, s2 = v * a.z, s3 = v * a.w;
        acc[0].x += s0 * hx; acc[0].y += s0 * hy;
        acc[1].x += s1 * hx; acc[1].y += s1 * hy;
        acc[2].x += s2 * hx; acc[2].y += s2 * hy;
        acc[3].x += s3 * hx; acc[3].y += s3 * hy;
    }

    unsigned short* arow = Agg + (size_t)wid * 512 + lane * 2;
#pragma unroll
    for (int b = 0; b < 4; ++b) {
        unsigned int pk = (unsigned int)f2bf(acc[b].x)
                        | ((unsigned int)f2bf(acc[b].y) << 16);
        *reinterpret_cast<unsigned int*>(arow + b * 128) = pk;
    }
}

// ---------------------------------------------------------------------------
// K_B: out = Agg @ V  (M=Ne, K=512, N=128), MFMA.
// ---------------------------------------------------------------------------
__global__ __launch_bounds__(512) void vgemm_kernel(
    const unsigned short* __restrict__ Agg,
    const unsigned short* __restrict__ VfragG,
    float* __restrict__ out, int Ne, int nTiles)
{
    __shared__ short8 ldsV[4096];   // [b][otl][ks][lane], 64 KB
    int half = blockIdx.x & 1;
    int blk  = blockIdx.x >> 1;
    int nblk = gridDim.x >> 1;
    int tid  = threadIdx.x;

    for (int i = tid; i < 4096; i += 512) {
        int lane = i & 63, ks = (i >> 6) & 3, otl = (i >> 8) & 3, b = i >> 10;
        int gi = ((b * 8 + half * 4 + otl) * 4 + ks) * 64 + lane;
        ldsV[i] = reinterpret_cast<const short8*>(VfragG)[gi];
    }
    __syncthreads();

    int wave = tid >> 6;
    int lane = tid & 63;
    int quad = lane >> 4, l15 = lane & 15;

    int wgid = blk * 8 + wave;
    int nw   = nblk * 8;

    for (int tile = wgid; tile < nTiles; tile += nw) {
        int node0 = tile * 16;
        int node  = node0 + l15;
        int rdnode = node < Ne ? node : Ne - 1;

        const short8* bp = reinterpret_cast<const short8*>(Agg)
                         + (size_t)rdnode * 64 + quad;
        short8 bf[16];
#pragma unroll
        for (int b = 0; b < 4; ++b)
#pragma unroll
            for (int ks = 0; ks < 4; ++ks)
                bf[b * 4 + ks] = bp[b * 16 + ks * 4];

        floatx4 acc[4];
#pragma unroll
        for (int o = 0; o < 4; ++o) acc[o] = (floatx4){0.f, 0.f, 0.f, 0.f};

#pragma unroll
        for (int b = 0; b < 4; ++b)
#pragma unroll
            for (int ks = 0; ks < 4; ++ks)
#pragma unroll
                for (int otl = 0; otl < 4; ++otl)
                    acc[otl] = __builtin_amdgcn_mfma_f32_16x16x32_bf16(
                        ldsV[((b * 4 + otl) * 4 + ks) * 64 + lane],
                        bf[b * 4 + ks], acc[otl], 0, 0, 0);

        if (node < Ne) {
            float* orow = out + (size_t)node * DIM + half * 64;
#pragma unroll
            for (int otl = 0; otl < 4; ++otl) {
                float4 st;
                st.x = acc[otl][0]; st.y = acc[otl][1];
                st.z = acc[otl][2]; st.w = acc[otl][3];
                *reinterpret_cast<float4*>(orow + otl * 16 + quad * 4) = st;
            }
        }
    }
}

// ---------------------------------------------------------------------------
// Fallback (ws too small): round-2 atomic kernel
// ---------------------------------------------------------------------------
__global__ __launch_bounds__(256) void rgcn_main(
    const unsigned short* __restrict__ Hbf,
    const unsigned short* __restrict__ Wfrag,
    const int*   __restrict__ erow,
    const int*   __restrict__ ecol,
    const float* __restrict__ eval,
    float*       __restrict__ out,
    int E, int groups_per_rel, int waves_per_rel)
{
    int wid  = blockIdx.x * 4 + (threadIdx.x >> 6);
    int lane = threadIdx.x & 63;
    int r    = wid & 7;
    int wr   = wid >> 3;
    int quad = lane >> 4;
    int l15  = lane & 15;

    short8 b[8][4];
    {
        const short8* wp = reinterpret_cast<const short8*>(
            Wfrag + (size_t)r * 16384);
#pragma unroll
        for (int ot = 0; ot < 8; ++ot)
#pragma unroll
            for (int ks = 0; ks < 4; ++ks)
                b[ot][ks] = wp[(ot * 4 + ks) * 64 + lane];
    }

    for (int g = wr; g < groups_per_rel; g += waves_per_rel) {
        int ebase = r * E + g * 16;
        int   colv = ecol[ebase + l15];
        int   rowv = erow[ebase + l15];
        float valv = eval[ebase + l15];

        short8 a[4];
        const unsigned short* hp = Hbf + (size_t)colv * DIM + quad * 8;
#pragma unroll
        for (int ks = 0; ks < 4; ++ks)
            a[ks] = *reinterpret_cast<const short8*>(hp + ks * 32);

        floatx4 acc[8];
#pragma unroll
        for (int ot = 0; ot < 8; ++ot) acc[ot] = (floatx4){0.f, 0.f, 0.f, 0.f};
#pragma unroll
        for (int ot = 0; ot < 8; ++ot)
#pragma unroll
            for (int ks = 0; ks < 4; ++ks)
                acc[ot] = __builtin_amdgcn_mfma_f32_16x16x32_bf16(
                    a[ks], b[ot][ks], acc[ot], 0, 0, 0);

        int   row4[4];
        float val4[4];
#pragma unroll
        for (int reg = 0; reg < 4; ++reg) {
            int src  = quad * 4 + reg;
            row4[reg] = __shfl(rowv, src, 64);
            val4[reg] = __shfl(valv, src, 64);
        }
#pragma unroll
        for (int ot = 0; ot < 8; ++ot)
#pragma unroll
            for (int reg = 0; reg < 4; ++reg) {
                float m = acc[ot][reg] * val4[reg];
                atomicAdd(out + (size_t)row4[reg] * DIM + ot * 16 + l15, m);
            }
    }
}

extern "C" void kernel_launch(void* const* d_in, const int* in_sizes, int n_in,
                              void* d_out, int out_size, void* d_ws, size_t ws_size,
                              hipStream_t stream)
{
    const float* H    = (const float*)d_in[0];
    const float* A    = (const float*)d_in[1];
    const float* V    = (const float*)d_in[2];
    const int*   erow = (const int*)d_in[3];
    const int*   ecol = (const int*)d_in[4];
    const float* eval = (const float*)d_in[5];
    float* out = (float*)d_out;

    int Ne    = in_sizes[0] / DIM;   // 100000
    int NEtot = in_sizes[3];         // 1.6M
    int E     = NEtot / NR;          // 200000

    auto al = [](size_t x) { return (x + 255) & ~(size_t)255; };

    int nbuc = (Ne + BROWS - 1) / BROWS;   // 196

    size_t offHbf    = 0;
    size_t offVfrag  = offHbf    + al((size_t)Ne * DIM * 2);
    size_t offWfrag  = offVfrag  + al((size_t)8192 * 16);
    size_t offAgg    = offWfrag  + al((size_t)16384 * 16);  // sorted1 aliases here
    size_t offRow    = offAgg    + al((size_t)Ne * 512 * 2);
    size_t offBcnt   = offRow    + al(((size_t)Ne + 2) * 4);
    size_t offBstart = offBcnt   + al((size_t)256 * 4);
    size_t offSort   = offBstart + al((size_t)256 * 4);
    size_t total     = offSort   + al((size_t)NEtot * 8);
    // sorted1 (196*16384*8 = 25.7 MB) aliases the Agg region (102.4 MB): it is
    // dead before agg_kernel writes Agg.

    char* ws = (char*)d_ws;
    unsigned short* Hbf    = (unsigned short*)(ws + offHbf);
    unsigned short* VfragG = (unsigned short*)(ws + offVfrag);
    unsigned short* Wfrag  = (unsigned short*)(ws + offWfrag);

    int n8 = Ne * DIM / 8;
    h_to_bf<<<(n8 + 255) / 256, 256, 0, stream>>>(H, Hbf, n8);

    if (ws_size < total) {
        // fallback: atomic-scatter path (round 2)
        build_wfrag<<<64, 256, 0, stream>>>(A, V, Wfrag);
        hipMemsetAsync(d_out, 0, (size_t)Ne * DIM * sizeof(float), stream);
        int blocks = 4096;
        int waves_per_rel = blocks * 4 / NR;
        int groups_per_rel = E / 16;
        rgcn_main<<<blocks, 256, 0, stream>>>(Hbf, Wfrag, erow, ecol, eval, out,
                                              E, groups_per_rel, waves_per_rel);
        return;
    }

    unsigned short* Agg      = (unsigned short*)(ws + offAgg);
    int2*           sorted1  = (int2*)(ws + offAgg);   // alias (dead before Agg)
    int*            rowStart = (int*)(ws + offRow);
    int*            bcnt     = (int*)(ws + offBcnt);
    int*            bstart   = (int*)(ws + offBstart);
    int2*           sorted   = (int2*)(ws + offSort);

    build_vfrag<<<32, 256, 0, stream>>>(V, VfragG);

    // two-level bucket sort (no global histogram / scan prologue)
    hipMemsetAsync(bcnt, 0, 256 * 4, stream);
    int sblocks = 512;
    int chunk   = (NEtot + sblocks - 1) / sblocks;   // 3125
    bucket_scatter<<<sblocks, 256, 0, stream>>>(erow, ecol, eval, bcnt,
                                                sorted1, NEtot, E, chunk);
    bucket_scan<<<1, 256, 0, stream>>>(bcnt, bstart, rowStart, nbuc, Ne);
    bucket_sort<<<nbuc, 256, 0, stream>>>(sorted1, bcnt, bstart, rowStart,
                                          sorted, Ne);

    // K_A: 4-basis aggregation (scalarized control path, no atomics)
    agg_kernel<<<(Ne + 3) / 4, 256, 0, stream>>>(Hbf, rowStart, sorted, A,
                                                 Agg, Ne);

    // K_B: out = Agg @ V via MFMA, V-frags in LDS (two 64-col halves)
    int nTiles = (Ne + 15) / 16;   // 6250
    vgemm_kernel<<<512, 512, 0, stream>>>(Agg, VfragG, out, Ne, nTiles);
}